// Round 1
// baseline (1434.249 us; speedup 1.0000x reference)
//
#include <hip/hip_runtime.h>
#include <cstdint>
#include <cmath>

// GPT-2 block: B=8, S=1024, D=1024, H=16, Hd=64.
// Pipeline: LN1 -> qkv GEMM -> flash attention -> proj GEMM(+residual)
//           -> LN2 -> fc GEMM(+GELU) -> proj2 GEMM(+residual) -> out (fp32)
// All GEMMs: bf16 MFMA 16x16x32, 128x128 tile, BK=32, global_load_lds width=16.

#define Bb 8
#define Ss 1024
#define Dd 1024
#define Hh 16
#define HD 64
#define MTOK 8192  // B*S

typedef __attribute__((ext_vector_type(4))) float  floatx4;
typedef __attribute__((ext_vector_type(8))) short  short8;

__device__ __forceinline__ float bf2f(unsigned short u) {
    return __uint_as_float(((unsigned int)u) << 16);
}
__device__ __forceinline__ unsigned short f2bf(float f) {
    unsigned int u = __float_as_uint(f);
    u += 0x7FFFu + ((u >> 16) & 1u);   // RNE
    return (unsigned short)(u >> 16);
}

__device__ __forceinline__ void gl2lds16(const void* g, void* l) {
    __builtin_amdgcn_global_load_lds(
        (__attribute__((address_space(1))) void*)(g),
        (__attribute__((address_space(3))) void*)(l),
        16, 0, 0);
}

// ---------------- weight transpose + fp32->bf16 ----------------
// W [K][N] fp32 -> WT [N][K] bf16
__global__ __launch_bounds__(256) void transpose_w(
    const float* __restrict__ W, unsigned short* __restrict__ WT, int K, int N)
{
    __shared__ float tile[32][33];
    int bx = blockIdx.x, by = blockIdx.y;
    int tx = threadIdx.x & 31;
    int ty = threadIdx.x >> 5;  // 0..7
    int col = bx * 32 + tx;
#pragma unroll
    for (int i = 0; i < 4; ++i) {
        int row = by * 32 + ty + i * 8;
        tile[ty + i * 8][tx] = W[(size_t)row * N + col];
    }
    __syncthreads();
#pragma unroll
    for (int i = 0; i < 4; ++i) {
        int n = bx * 32 + ty + i * 8;
        WT[(size_t)n * K + by * 32 + tx] = f2bf(tile[tx][ty + i * 8]);
    }
}

// ---------------- layernorm fp32 -> bf16 ----------------
__global__ __launch_bounds__(256) void layernorm_bf16(
    const float* __restrict__ X, const float* __restrict__ g,
    const float* __restrict__ b, unsigned short* __restrict__ Y)
{
    int row = blockIdx.x, t = threadIdx.x;
    const float4* xr = (const float4*)(X + (size_t)row * Dd);
    float4 v = xr[t];
    float s  = v.x + v.y + v.z + v.w;
    float s2 = v.x * v.x + v.y * v.y + v.z * v.z + v.w * v.w;
#pragma unroll
    for (int off = 32; off >= 1; off >>= 1) {
        s  += __shfl_down(s, off, 64);
        s2 += __shfl_down(s2, off, 64);
    }
    __shared__ float red[8];
    int wave = t >> 6, lane = t & 63;
    if (lane == 0) { red[wave] = s; red[4 + wave] = s2; }
    __syncthreads();
    float ts  = red[0] + red[1] + red[2] + red[3];
    float ts2 = red[4] + red[5] + red[6] + red[7];
    float mu  = ts * (1.0f / Dd);
    float var = ts2 * (1.0f / Dd) - mu * mu;
    float rstd = rsqrtf(var + 1e-5f);
    float4 gv = ((const float4*)g)[t];
    float4 bv = ((const float4*)b)[t];
    ushort4 o;
    o.x = f2bf((v.x - mu) * rstd * gv.x + bv.x);
    o.y = f2bf((v.y - mu) * rstd * gv.y + bv.y);
    o.z = f2bf((v.z - mu) * rstd * gv.z + bv.z);
    o.w = f2bf((v.w - mu) * rstd * gv.w + bv.w);
    ((ushort4*)(Y + (size_t)row * Dd))[t] = o;
}

// ---------------- GEMM: C = A[M,K] * BT[N,K]^T + bias, fused epilogues ----
// MODE 0: out bf16 = A@B + bias
// MODE 1: out fp32 = A@B + bias + res
// MODE 2: out bf16 = gelu_new(A@B + bias)
template <int MODE>
__global__ __launch_bounds__(256, 2) void gemm_bt(
    const unsigned short* __restrict__ A,   // [M][K] bf16
    const unsigned short* __restrict__ BT,  // [N][K] bf16
    const float* __restrict__ bias,         // [N]
    const float* __restrict__ res,          // [M][N] fp32 (MODE 1)
    void* __restrict__ out,
    int M, int N, int K)
{
    __shared__ short As[128 * 32];  // 8 KB
    __shared__ short Bs[128 * 32];  // 8 KB
    const int tid  = threadIdx.x;
    const int wave = tid >> 6, lane = tid & 63;
    const int quad = lane >> 4, l16 = lane & 15;
    const int wm = (wave >> 1) * 64, wn = (wave & 1) * 64;
    const size_t rowA0 = (size_t)blockIdx.x * 128;
    const size_t rowB0 = (size_t)blockIdx.y * 128;

    floatx4 acc[4][4] = {};

    const int idx0 = tid, idx1 = tid + 256;
    const int ra0 = idx0 >> 2, ca0 = (idx0 & 3) * 8;
    const int ra1 = idx1 >> 2, ca1 = (idx1 & 3) * 8;

    for (int k0 = 0; k0 < K; k0 += 32) {
        gl2lds16(A  + (rowA0 + ra0) * K + k0 + ca0, As + idx0 * 8);
        gl2lds16(A  + (rowA0 + ra1) * K + k0 + ca1, As + idx1 * 8);
        gl2lds16(BT + (rowB0 + ra0) * K + k0 + ca0, Bs + idx0 * 8);
        gl2lds16(BT + (rowB0 + ra1) * K + k0 + ca1, Bs + idx1 * 8);
        __syncthreads();
        short8 af[4], bfr[4];
#pragma unroll
        for (int mi = 0; mi < 4; ++mi)
            af[mi] = *(const short8*)(As + (wm + mi * 16 + l16) * 32 + quad * 8);
#pragma unroll
        for (int ni = 0; ni < 4; ++ni)
            bfr[ni] = *(const short8*)(Bs + (wn + ni * 16 + l16) * 32 + quad * 8);
#pragma unroll
        for (int mi = 0; mi < 4; ++mi)
#pragma unroll
            for (int ni = 0; ni < 4; ++ni)
                acc[mi][ni] = __builtin_amdgcn_mfma_f32_16x16x32_bf16(
                    af[mi], bfr[ni], acc[mi][ni], 0, 0, 0);
        __syncthreads();
    }

#pragma unroll
    for (int mi = 0; mi < 4; ++mi) {
#pragma unroll
        for (int ni = 0; ni < 4; ++ni) {
            size_t row = rowA0 + wm + mi * 16 + quad * 4;
            size_t col = rowB0 + wn + ni * 16 + l16;
            float bc = bias[col];
#pragma unroll
            for (int r = 0; r < 4; ++r) {
                float v = acc[mi][ni][r] + bc;
                if (MODE == 0) {
                    ((unsigned short*)out)[(row + r) * N + col] = f2bf(v);
                } else if (MODE == 1) {
                    ((float*)out)[(row + r) * N + col] = v + res[(row + r) * N + col];
                } else {
                    float t  = tanhf(0.7978845608028654f * (v + 0.044715f * v * v * v));
                    float gl = 0.5f * v * (1.0f + t);
                    ((unsigned short*)out)[(row + r) * N + col] = f2bf(gl);
                }
            }
        }
    }
}

// ---------------- flash attention (fp32 vector, causal) ----------------
// Grid: B*H*4 blocks of 256 threads. Each thread owns one query row.
// Block (b,h,qt) owns query chunks {qt, 7-qt} of 128 rows each -> uniform work.
__global__ __launch_bounds__(256, 2) void attn_flash(
    const unsigned short* __restrict__ qkv,  // [B*S][3072] bf16, q|k|v
    unsigned short* __restrict__ ctx)        // [B*S][1024] bf16
{
    __shared__ float Ks[64][68];
    __shared__ float Vs[64][68];
    int tid = threadIdx.x;
    int blk = blockIdx.x;
    int qt = blk & 3, h = (blk >> 2) & 15, b = blk >> 6;
    int half = tid >> 7, r = tid & 127;
    int chunk = half ? (7 - qt) : qt;
    int q = chunk * 128 + r;
    int nkt = (8 - qt) * 2;  // key tiles of 64 (covers max q in block)

    floatx4 q4[16];
    {
        const short8* qp = (const short8*)(qkv + ((size_t)(b * Ss + q)) * 3072 + h * HD);
#pragma unroll
        for (int i = 0; i < 8; ++i) {
            short8 c = qp[i];
            floatx4 a, d;
            a[0] = bf2f((unsigned short)c[0]); a[1] = bf2f((unsigned short)c[1]);
            a[2] = bf2f((unsigned short)c[2]); a[3] = bf2f((unsigned short)c[3]);
            d[0] = bf2f((unsigned short)c[4]); d[1] = bf2f((unsigned short)c[5]);
            d[2] = bf2f((unsigned short)c[6]); d[3] = bf2f((unsigned short)c[7]);
            q4[2 * i] = a; q4[2 * i + 1] = d;
        }
    }
    floatx4 O4[16];
#pragma unroll
    for (int i = 0; i < 16; ++i) { floatx4 z = {0.f, 0.f, 0.f, 0.f}; O4[i] = z; }
    float mrun = -__builtin_inff(), lrun = 0.f;

    int rr = tid >> 2, cc = (tid & 3) * 16;
    for (int kt = 0; kt < nkt; ++kt) {
        __syncthreads();
        {
            const unsigned short* kb =
                qkv + ((size_t)(b * Ss + kt * 64 + rr)) * 3072 + Dd + h * HD + cc;
            const short8* kp = (const short8*)kb;
            const short8* vp = (const short8*)(kb + Dd);
            short8 k0 = kp[0], k1 = kp[1], v0 = vp[0], v1 = vp[1];
#pragma unroll
            for (int j = 0; j < 8; ++j) {
                Ks[rr][cc + j]     = bf2f((unsigned short)k0[j]);
                Ks[rr][cc + 8 + j] = bf2f((unsigned short)k1[j]);
                Vs[rr][cc + j]     = bf2f((unsigned short)v0[j]);
                Vs[rr][cc + 8 + j] = bf2f((unsigned short)v1[j]);
            }
        }
        __syncthreads();
        if (q >= kt * 64) {
            for (int jt = 0; jt < 8; ++jt) {
                float s8[8], ps[8];
#pragma unroll
                for (int jj = 0; jj < 8; ++jj) {
                    int j = jt * 8 + jj;
                    const floatx4* Kr = (const floatx4*)(&Ks[j][0]);
                    floatx4 a = q4[0] * Kr[0];
#pragma unroll
                    for (int d4 = 1; d4 < 16; ++d4) a += q4[d4] * Kr[d4];
                    float sj = (a[0] + a[1]) + (a[2] + a[3]);
                    s8[jj] = (kt * 64 + j <= q) ? sj * 0.125f : -__builtin_inff();
                }
                float mt = s8[0];
#pragma unroll
                for (int jj = 1; jj < 8; ++jj) mt = fmaxf(mt, s8[jj]);
                float mnew  = fmaxf(mrun, mt);
                float alpha = __expf(mrun - mnew);
                float lsum = 0.f;
#pragma unroll
                for (int jj = 0; jj < 8; ++jj) { ps[jj] = __expf(s8[jj] - mnew); lsum += ps[jj]; }
                lrun = lrun * alpha + lsum;
#pragma unroll
                for (int i = 0; i < 16; ++i) O4[i] *= alpha;
#pragma unroll
                for (int jj = 0; jj < 8; ++jj) {
                    const floatx4* Vr = (const floatx4*)(&Vs[jt * 8 + jj][0]);
                    float p = ps[jj];
#pragma unroll
                    for (int i = 0; i < 16; ++i) O4[i] += p * Vr[i];
                }
                mrun = mnew;
            }
        }
    }
    float inv = 1.0f / lrun;
    unsigned short* op = ctx + ((size_t)(b * Ss + q)) * Dd + h * HD;
#pragma unroll
    for (int i = 0; i < 8; ++i) {
        floatx4 a = O4[2 * i] * inv, d = O4[2 * i + 1] * inv;
        short8 o;
        o[0] = (short)f2bf(a[0]); o[1] = (short)f2bf(a[1]);
        o[2] = (short)f2bf(a[2]); o[3] = (short)f2bf(a[3]);
        o[4] = (short)f2bf(d[0]); o[5] = (short)f2bf(d[1]);
        o[6] = (short)f2bf(d[2]); o[7] = (short)f2bf(d[3]);
        ((short8*)op)[i] = o;
    }
}

// ---------------- launch ----------------
extern "C" void kernel_launch(void* const* d_in, const int* in_sizes, int n_in,
                              void* d_out, int out_size, void* d_ws, size_t ws_size,
                              hipStream_t stream)
{
    const float* x        = (const float*)d_in[0];
    const float* ln1_g    = (const float*)d_in[1];
    const float* ln1_b    = (const float*)d_in[2];
    const float* c_attn_w = (const float*)d_in[3];
    const float* c_attn_b = (const float*)d_in[4];
    const float* c_proj_w = (const float*)d_in[5];
    const float* c_proj_b = (const float*)d_in[6];
    const float* ln2_g    = (const float*)d_in[7];
    const float* ln2_b    = (const float*)d_in[8];
    const float* fc_w     = (const float*)d_in[9];
    const float* fc_b     = (const float*)d_in[10];
    const float* proj_w   = (const float*)d_in[11];
    const float* proj_b   = (const float*)d_in[12];
    float* out = (float*)d_out;

    char* p = (char*)d_ws;
    auto alloc = [&](size_t bytes) {
        void* r = (void*)p;
        p += (bytes + 255) & ~(size_t)255;
        return r;
    };
    unsigned short* WaT  = (unsigned short*)alloc((size_t)3072 * 1024 * 2);
    unsigned short* WpT  = (unsigned short*)alloc((size_t)1024 * 1024 * 2);
    unsigned short* WfT  = (unsigned short*)alloc((size_t)4096 * 1024 * 2);
    unsigned short* Wp2T = (unsigned short*)alloc((size_t)1024 * 4096 * 2);
    unsigned short* h1   = (unsigned short*)alloc((size_t)MTOK * 1024 * 2);
    unsigned short* qkv  = (unsigned short*)alloc((size_t)MTOK * 3072 * 2);
    unsigned short* ctx  = (unsigned short*)alloc((size_t)MTOK * 1024 * 2);
    float*          hmid = (float*)alloc((size_t)MTOK * 1024 * 4);
    unsigned short* h2   = (unsigned short*)alloc((size_t)MTOK * 1024 * 2);
    unsigned short* ff1  = (unsigned short*)alloc((size_t)MTOK * 4096 * 2);

    transpose_w<<<dim3(3072 / 32, 1024 / 32), 256, 0, stream>>>(c_attn_w, WaT, 1024, 3072);
    transpose_w<<<dim3(1024 / 32, 1024 / 32), 256, 0, stream>>>(c_proj_w, WpT, 1024, 1024);
    transpose_w<<<dim3(4096 / 32, 1024 / 32), 256, 0, stream>>>(fc_w, WfT, 1024, 4096);
    transpose_w<<<dim3(1024 / 32, 4096 / 32), 256, 0, stream>>>(proj_w, Wp2T, 4096, 1024);

    layernorm_bf16<<<MTOK, 256, 0, stream>>>(x, ln1_g, ln1_b, h1);
    gemm_bt<0><<<dim3(64, 24), 256, 0, stream>>>(h1, WaT, c_attn_b, nullptr, qkv, MTOK, 3072, 1024);
    attn_flash<<<Bb * Hh * 4, 256, 0, stream>>>(qkv, ctx);
    gemm_bt<1><<<dim3(64, 8), 256, 0, stream>>>(ctx, WpT, c_proj_b, x, hmid, MTOK, 1024, 1024);
    layernorm_bf16<<<MTOK, 256, 0, stream>>>(hmid, ln2_g, ln2_b, h2);
    gemm_bt<2><<<dim3(64, 32), 256, 0, stream>>>(h2, WfT, fc_b, nullptr, ff1, MTOK, 4096, 1024);
    gemm_bt<1><<<dim3(64, 8), 256, 0, stream>>>(ff1, Wp2T, proj_b, hmid, out, MTOK, 1024, 4096);
}

// Round 2
// 517.782 us; speedup vs baseline: 2.7700x; 2.7700x over previous
//
#include <hip/hip_runtime.h>
#include <cstdint>
#include <cmath>

// GPT-2 block: B=8, S=1024, D=1024, H=16, Hd=64.
// LN1 -> qkv GEMM -> MFMA flash attention -> proj GEMM(+res) -> LN2
//     -> fc GEMM(+GELU) -> proj2 GEMM(+res) -> out (fp32)

#define Bb 8
#define Ss 1024
#define Dd 1024
#define Hh 16
#define HD 64
#define MTOK 8192  // B*S

typedef __attribute__((ext_vector_type(4))) float  floatx4;
typedef __attribute__((ext_vector_type(8))) short  short8;
typedef __attribute__((ext_vector_type(4))) short  short4v;

__device__ __forceinline__ float bf2f(unsigned short u) {
    return __uint_as_float(((unsigned int)u) << 16);
}
__device__ __forceinline__ unsigned short f2bf(float f) {
    unsigned int u = __float_as_uint(f);
    u += 0x7FFFu + ((u >> 16) & 1u);   // RNE
    return (unsigned short)(u >> 16);
}

__device__ __forceinline__ void gl2lds16(const void* g, void* l) {
    __builtin_amdgcn_global_load_lds(
        (__attribute__((address_space(1))) void*)(g),
        (__attribute__((address_space(3))) void*)(l),
        16, 0, 0);
}

// ---------------- weight transpose + fp32->bf16 ----------------
__global__ __launch_bounds__(256) void transpose_w(
    const float* __restrict__ W, unsigned short* __restrict__ WT, int K, int N)
{
    __shared__ float tile[32][33];
    int bx = blockIdx.x, by = blockIdx.y;
    int tx = threadIdx.x & 31;
    int ty = threadIdx.x >> 5;
    int col = bx * 32 + tx;
#pragma unroll
    for (int i = 0; i < 4; ++i) {
        int row = by * 32 + ty + i * 8;
        tile[ty + i * 8][tx] = W[(size_t)row * N + col];
    }
    __syncthreads();
#pragma unroll
    for (int i = 0; i < 4; ++i) {
        int n = bx * 32 + ty + i * 8;
        WT[(size_t)n * K + by * 32 + tx] = f2bf(tile[tx][ty + i * 8]);
    }
}

// ---------------- layernorm fp32 -> bf16 ----------------
__global__ __launch_bounds__(256) void layernorm_bf16(
    const float* __restrict__ X, const float* __restrict__ g,
    const float* __restrict__ b, unsigned short* __restrict__ Y)
{
    int row = blockIdx.x, t = threadIdx.x;
    const float4* xr = (const float4*)(X + (size_t)row * Dd);
    float4 v = xr[t];
    float s  = v.x + v.y + v.z + v.w;
    float s2 = v.x * v.x + v.y * v.y + v.z * v.z + v.w * v.w;
#pragma unroll
    for (int off = 32; off >= 1; off >>= 1) {
        s  += __shfl_down(s, off, 64);
        s2 += __shfl_down(s2, off, 64);
    }
    __shared__ float red[8];
    int wave = t >> 6, lane = t & 63;
    if (lane == 0) { red[wave] = s; red[4 + wave] = s2; }
    __syncthreads();
    float ts  = red[0] + red[1] + red[2] + red[3];
    float ts2 = red[4] + red[5] + red[6] + red[7];
    float mu  = ts * (1.0f / Dd);
    float var = ts2 * (1.0f / Dd) - mu * mu;
    float rstd = rsqrtf(var + 1e-5f);
    float4 gv = ((const float4*)g)[t];
    float4 bv = ((const float4*)b)[t];
    ushort4 o;
    o.x = f2bf((v.x - mu) * rstd * gv.x + bv.x);
    o.y = f2bf((v.y - mu) * rstd * gv.y + bv.y);
    o.z = f2bf((v.z - mu) * rstd * gv.z + bv.z);
    o.w = f2bf((v.w - mu) * rstd * gv.w + bv.w);
    ((ushort4*)(Y + (size_t)row * Dd))[t] = o;
}

// ---------------- GEMM: C = A[M,K] * BT[N,K]^T + bias ----------------
// MODE 0: out bf16 = A@B + bias
// MODE 1: out fp32 = A@B + bias + res
// MODE 2: out bf16 = gelu_new(A@B + bias)
template <int MODE>
__global__ __launch_bounds__(256, 2) void gemm_bt(
    const unsigned short* __restrict__ A,
    const unsigned short* __restrict__ BT,
    const float* __restrict__ bias,
    const float* __restrict__ res,
    void* __restrict__ out,
    int M, int N, int K)
{
    __shared__ short As[128 * 32];
    __shared__ short Bs[128 * 32];
    const int tid  = threadIdx.x;
    const int wave = tid >> 6, lane = tid & 63;
    const int quad = lane >> 4, l16 = lane & 15;
    const int wm = (wave >> 1) * 64, wn = (wave & 1) * 64;
    const size_t rowA0 = (size_t)blockIdx.x * 128;
    const size_t rowB0 = (size_t)blockIdx.y * 128;

    floatx4 acc[4][4] = {};

    const int idx0 = tid, idx1 = tid + 256;
    const int ra0 = idx0 >> 2, ca0 = (idx0 & 3) * 8;
    const int ra1 = idx1 >> 2, ca1 = (idx1 & 3) * 8;

    for (int k0 = 0; k0 < K; k0 += 32) {
        gl2lds16(A  + (rowA0 + ra0) * K + k0 + ca0, As + idx0 * 8);
        gl2lds16(A  + (rowA0 + ra1) * K + k0 + ca1, As + idx1 * 8);
        gl2lds16(BT + (rowB0 + ra0) * K + k0 + ca0, Bs + idx0 * 8);
        gl2lds16(BT + (rowB0 + ra1) * K + k0 + ca1, Bs + idx1 * 8);
        __syncthreads();
        short8 af[4], bfr[4];
#pragma unroll
        for (int mi = 0; mi < 4; ++mi)
            af[mi] = *(const short8*)(As + (wm + mi * 16 + l16) * 32 + quad * 8);
#pragma unroll
        for (int ni = 0; ni < 4; ++ni)
            bfr[ni] = *(const short8*)(Bs + (wn + ni * 16 + l16) * 32 + quad * 8);
#pragma unroll
        for (int mi = 0; mi < 4; ++mi)
#pragma unroll
            for (int ni = 0; ni < 4; ++ni)
                acc[mi][ni] = __builtin_amdgcn_mfma_f32_16x16x32_bf16(
                    af[mi], bfr[ni], acc[mi][ni], 0, 0, 0);
        __syncthreads();
    }

#pragma unroll
    for (int mi = 0; mi < 4; ++mi) {
#pragma unroll
        for (int ni = 0; ni < 4; ++ni) {
            size_t row = rowA0 + wm + mi * 16 + quad * 4;
            size_t col = rowB0 + wn + ni * 16 + l16;
            float bc = bias[col];
#pragma unroll
            for (int r = 0; r < 4; ++r) {
                float v = acc[mi][ni][r] + bc;
                if (MODE == 0) {
                    ((unsigned short*)out)[(row + r) * N + col] = f2bf(v);
                } else if (MODE == 1) {
                    ((float*)out)[(row + r) * N + col] = v + res[(row + r) * N + col];
                } else {
                    float t  = tanhf(0.7978845608028654f * (v + 0.044715f * v * v * v));
                    float gl = 0.5f * v * (1.0f + t);
                    ((unsigned short*)out)[(row + r) * N + col] = f2bf(gl);
                }
            }
        }
    }
}

// ---------------- MFMA flash attention (causal) ----------------
// Grid: B*H*4 = 512 blocks of 256 threads. Block (b,h,c4) processes query
// chunks {c4, 7-c4} of 128 rows -> uniform 18 K-tiles (64 keys each) per block.
// Per K-tile: S^T = K.Q^T (MFMA, C-frag cols = queries -> per-lane softmax
// state), P^T written to LDS as b64 chunks, O^T = V^T.P^T (MFMA, both
// operands b128 from LDS). Q pre-scaled by 0.125*log2(e); softmax in exp2.
__global__ __launch_bounds__(256, 2) void attn_mfma(
    const unsigned short* __restrict__ qkv,  // [B*S][3072] bf16 q|k|v
    unsigned short* __restrict__ ctx)        // [B*S][1024] bf16
{
    __shared__ unsigned short Ks[64 * 72];   // K tile [key][d], stride 72
    __shared__ unsigned short VT[64 * 72];   // V^T tile [d][key]
    __shared__ unsigned short PT[128 * 72];  // P^T as [q][key], wave-private rows

    const int tid  = threadIdx.x;
    const int wave = tid >> 6, lane = tid & 63;
    const int quad = lane >> 4, l16 = lane & 15;
    const int blk = blockIdx.x;
    const int c4 = blk & 3, h = (blk >> 2) & 15, b = blk >> 6;
    const size_t tokbase = (size_t)b * Ss;

    const int skey = tid & 63;   // staging: key row
    const int sseg = tid >> 6;   // staging: d-segment *16

    for (int ci = 0; ci < 2; ++ci) {
        const int chunk = ci ? (7 - c4) : c4;
        const int q0 = chunk * 128;

        // Q fragments (B-operand), scaled by 0.125*log2(e) (exact-ish in fp32)
        short8 qf[2][2];  // [nb][ks]
#pragma unroll
        for (int nb = 0; nb < 2; ++nb)
#pragma unroll
            for (int ks = 0; ks < 2; ++ks) {
                const short8* qp = (const short8*)(qkv
                    + (tokbase + q0 + wave * 32 + nb * 16 + l16) * 3072
                    + h * HD + ks * 32 + quad * 8);
                short8 v = *qp, o;
#pragma unroll
                for (int j = 0; j < 8; ++j)
                    o[j] = (short)f2bf(bf2f((unsigned short)v[j]) * 0.18033688011112042f);
                qf[nb][ks] = o;
            }

        floatx4 Oacc[4][2] = {};                 // [mi3 d-block][nb q-block]
        float mrow[2] = {-3.0e38f, -3.0e38f};
        float lrow[2] = {0.f, 0.f};

        const int nkt = 2 * (chunk + 1);
        for (int kt = 0; kt < nkt; ++kt) {
            __syncthreads();   // previous tile's Ks/VT reads done
            {
                const short8* kp = (const short8*)(qkv
                    + (tokbase + kt * 64 + skey) * 3072 + Dd + h * HD + sseg * 16);
                short8 k0 = kp[0], k1 = kp[1];
                *(short8*)(Ks + skey * 72 + sseg * 16)     = k0;
                *(short8*)(Ks + skey * 72 + sseg * 16 + 8) = k1;
                const short8* vp = (const short8*)(qkv
                    + (tokbase + kt * 64 + skey) * 3072 + 2 * Dd + h * HD + sseg * 16);
                short8 v0 = vp[0], v1 = vp[1];
#pragma unroll
                for (int j = 0; j < 8; ++j) {
                    VT[(sseg * 16 + j) * 72 + skey]     = (unsigned short)v0[j];
                    VT[(sseg * 16 + 8 + j) * 72 + skey] = (unsigned short)v1[j];
                }
            }
            __syncthreads();   // staging visible

            // S^T = K . Q^T : 64 keys x 32 queries per wave
            floatx4 sacc[4][2] = {};  // [mi2 key-block][nb]
#pragma unroll
            for (int ks = 0; ks < 2; ++ks) {
                short8 af[4];
#pragma unroll
                for (int mi = 0; mi < 4; ++mi)
                    af[mi] = *(const short8*)(Ks + (mi * 16 + l16) * 72 + ks * 32 + quad * 8);
#pragma unroll
                for (int mi = 0; mi < 4; ++mi)
#pragma unroll
                    for (int nb = 0; nb < 2; ++nb)
                        sacc[mi][nb] = __builtin_amdgcn_mfma_f32_16x16x32_bf16(
                            af[mi], qf[nb][ks], sacc[mi][nb], 0, 0, 0);
            }

            // causal mask (only the last two tiles of the chunk need it)
            if (kt >= 2 * chunk) {
                const int dk = (kt - 2 * chunk) * 64;
#pragma unroll
                for (int nb = 0; nb < 2; ++nb) {
                    int qrow = wave * 32 + nb * 16 + l16;
#pragma unroll
                    for (int mi = 0; mi < 4; ++mi)
#pragma unroll
                        for (int r = 0; r < 4; ++r)
                            if (dk + mi * 16 + quad * 4 + r > qrow)
                                sacc[mi][nb][r] = -3.0e38f;
                }
            }

            // online softmax per query column (state is per-lane!)
#pragma unroll
            for (int nb = 0; nb < 2; ++nb) {
                float mx = sacc[0][nb][0];
#pragma unroll
                for (int mi = 0; mi < 4; ++mi)
#pragma unroll
                    for (int r = 0; r < 4; ++r) mx = fmaxf(mx, sacc[mi][nb][r]);
                mx = fmaxf(mx, __shfl_xor(mx, 16, 64));
                mx = fmaxf(mx, __shfl_xor(mx, 32, 64));
                float mnew  = fmaxf(mrow[nb], mx);
                float alpha = exp2f(mrow[nb] - mnew);
                float ls = 0.f;
#pragma unroll
                for (int mi = 0; mi < 4; ++mi) {
                    short4v pk;
#pragma unroll
                    for (int r = 0; r < 4; ++r) {
                        float p = exp2f(sacc[mi][nb][r] - mnew);
                        ls += p;
                        pk[r] = (short)f2bf(p);
                    }
                    *(short4v*)(PT + (wave * 32 + nb * 16 + l16) * 72 + mi * 16 + quad * 4) = pk;
                }
                ls += __shfl_xor(ls, 16, 64);
                ls += __shfl_xor(ls, 32, 64);
                lrow[nb] = lrow[nb] * alpha + ls;
                mrow[nb] = mnew;
#pragma unroll
                for (int mi3 = 0; mi3 < 4; ++mi3) Oacc[mi3][nb] *= alpha;
            }
            // drain this wave's PT writes (region is wave-private -> no barrier)
            asm volatile("s_waitcnt lgkmcnt(0)" ::: "memory");

            // O^T += V^T . P^T
#pragma unroll
            for (int ks2 = 0; ks2 < 2; ++ks2) {
                short8 av[4], bp[2];
#pragma unroll
                for (int mi3 = 0; mi3 < 4; ++mi3)
                    av[mi3] = *(const short8*)(VT + (mi3 * 16 + l16) * 72 + ks2 * 32 + quad * 8);
#pragma unroll
                for (int nb = 0; nb < 2; ++nb)
                    bp[nb] = *(const short8*)(PT + (wave * 32 + nb * 16 + l16) * 72 + ks2 * 32 + quad * 8);
#pragma unroll
                for (int mi3 = 0; mi3 < 4; ++mi3)
#pragma unroll
                    for (int nb = 0; nb < 2; ++nb)
                        Oacc[mi3][nb] = __builtin_amdgcn_mfma_f32_16x16x32_bf16(
                            av[mi3], bp[nb], Oacc[mi3][nb], 0, 0, 0);
            }
        }

        // epilogue: O^T -> [q][d] via wave-private LDS, then coalesced store
#pragma unroll
        for (int nb = 0; nb < 2; ++nb) {
            float inv = 1.0f / lrow[nb];
#pragma unroll
            for (int mi3 = 0; mi3 < 4; ++mi3) {
                short4v ov;
#pragma unroll
                for (int r = 0; r < 4; ++r)
                    ov[r] = (short)f2bf(Oacc[mi3][nb][r] * inv);
                *(short4v*)(PT + (wave * 32 + nb * 16 + l16) * 72 + mi3 * 16 + quad * 4) = ov;
            }
        }
        asm volatile("s_waitcnt lgkmcnt(0)" ::: "memory");
        {
            int ql = lane >> 1, dbase = (lane & 1) * 32;
            unsigned short* op = ctx + (tokbase + q0 + wave * 32 + ql) * Dd + h * HD + dbase;
            const unsigned short* lp = PT + (wave * 32 + ql) * 72 + dbase;
#pragma unroll
            for (int i = 0; i < 4; ++i)
                ((short8*)op)[i] = *(const short8*)(lp + i * 8);
        }
    }
}

// ---------------- launch ----------------
extern "C" void kernel_launch(void* const* d_in, const int* in_sizes, int n_in,
                              void* d_out, int out_size, void* d_ws, size_t ws_size,
                              hipStream_t stream)
{
    const float* x        = (const float*)d_in[0];
    const float* ln1_g    = (const float*)d_in[1];
    const float* ln1_b    = (const float*)d_in[2];
    const float* c_attn_w = (const float*)d_in[3];
    const float* c_attn_b = (const float*)d_in[4];
    const float* c_proj_w = (const float*)d_in[5];
    const float* c_proj_b = (const float*)d_in[6];
    const float* ln2_g    = (const float*)d_in[7];
    const float* ln2_b    = (const float*)d_in[8];
    const float* fc_w     = (const float*)d_in[9];
    const float* fc_b     = (const float*)d_in[10];
    const float* proj_w   = (const float*)d_in[11];
    const float* proj_b   = (const float*)d_in[12];
    float* out = (float*)d_out;

    char* p = (char*)d_ws;
    auto alloc = [&](size_t bytes) {
        void* r = (void*)p;
        p += (bytes + 255) & ~(size_t)255;
        return r;
    };
    unsigned short* WaT  = (unsigned short*)alloc((size_t)3072 * 1024 * 2);
    unsigned short* WpT  = (unsigned short*)alloc((size_t)1024 * 1024 * 2);
    unsigned short* WfT  = (unsigned short*)alloc((size_t)4096 * 1024 * 2);
    unsigned short* Wp2T = (unsigned short*)alloc((size_t)1024 * 4096 * 2);
    unsigned short* h1   = (unsigned short*)alloc((size_t)MTOK * 1024 * 2);
    unsigned short* qkv  = (unsigned short*)alloc((size_t)MTOK * 3072 * 2);
    unsigned short* ctx  = (unsigned short*)alloc((size_t)MTOK * 1024 * 2);
    float*          hmid = (float*)alloc((size_t)MTOK * 1024 * 4);
    unsigned short* h2   = (unsigned short*)alloc((size_t)MTOK * 1024 * 2);
    unsigned short* ff1  = (unsigned short*)alloc((size_t)MTOK * 4096 * 2);

    transpose_w<<<dim3(3072 / 32, 1024 / 32), 256, 0, stream>>>(c_attn_w, WaT, 1024, 3072);
    transpose_w<<<dim3(1024 / 32, 1024 / 32), 256, 0, stream>>>(c_proj_w, WpT, 1024, 1024);
    transpose_w<<<dim3(4096 / 32, 1024 / 32), 256, 0, stream>>>(fc_w, WfT, 1024, 4096);
    transpose_w<<<dim3(1024 / 32, 4096 / 32), 256, 0, stream>>>(proj_w, Wp2T, 4096, 1024);

    layernorm_bf16<<<MTOK, 256, 0, stream>>>(x, ln1_g, ln1_b, h1);
    gemm_bt<0><<<dim3(64, 24), 256, 0, stream>>>(h1, WaT, c_attn_b, nullptr, qkv, MTOK, 3072, 1024);
    attn_mfma<<<Bb * Hh * 4, 256, 0, stream>>>(qkv, ctx);
    gemm_bt<1><<<dim3(64, 8), 256, 0, stream>>>(ctx, WpT, c_proj_b, x, hmid, MTOK, 1024, 1024);
    layernorm_bf16<<<MTOK, 256, 0, stream>>>(hmid, ln2_g, ln2_b, h2);
    gemm_bt<2><<<dim3(64, 32), 256, 0, stream>>>(h2, WfT, fc_b, nullptr, ff1, MTOK, 4096, 1024);
    gemm_bt<1><<<dim3(64, 8), 256, 0, stream>>>(ff1, Wp2T, proj_b, hmid, out, MTOK, 1024, 4096);
}

// Round 3
// 455.987 us; speedup vs baseline: 3.1454x; 1.1355x over previous
//
#include <hip/hip_runtime.h>
#include <cstdint>
#include <cmath>

// GPT-2 block: B=8, S=1024, D=1024, H=16, Hd=64.
// LN1 -> qkv GEMM -> MFMA flash attention -> proj GEMM(+res) -> LN2
//     -> fc GEMM(+fast GELU) -> proj2 GEMM(+res) -> out (fp32)
// GEMM: bf16 MFMA 16x16x32, 128x128 tile, BK=64, XOR-swizzled LDS
// (conflict-free ds_read_b128 with linear global_load_lds staging).

#define Bb 8
#define Ss 1024
#define Dd 1024
#define Hh 16
#define HD 64
#define MTOK 8192  // B*S

typedef __attribute__((ext_vector_type(4))) float  floatx4;
typedef __attribute__((ext_vector_type(8))) short  short8;
typedef __attribute__((ext_vector_type(4))) short  short4v;

__device__ __forceinline__ float bf2f(unsigned short u) {
    return __uint_as_float(((unsigned int)u) << 16);
}
__device__ __forceinline__ unsigned short f2bf(float f) {
    unsigned int u = __float_as_uint(f);
    u += 0x7FFFu + ((u >> 16) & 1u);   // RNE
    return (unsigned short)(u >> 16);
}

__device__ __forceinline__ void gl2lds16(const void* g, void* l) {
    __builtin_amdgcn_global_load_lds(
        (__attribute__((address_space(1))) void*)(g),
        (__attribute__((address_space(3))) void*)(l),
        16, 0, 0);
}

// ---------------- weight transpose + fp32->bf16 ----------------
__global__ __launch_bounds__(256) void transpose_w(
    const float* __restrict__ W, unsigned short* __restrict__ WT, int K, int N)
{
    __shared__ float tile[32][33];
    int bx = blockIdx.x, by = blockIdx.y;
    int tx = threadIdx.x & 31;
    int ty = threadIdx.x >> 5;
    int col = bx * 32 + tx;
#pragma unroll
    for (int i = 0; i < 4; ++i) {
        int row = by * 32 + ty + i * 8;
        tile[ty + i * 8][tx] = W[(size_t)row * N + col];
    }
    __syncthreads();
#pragma unroll
    for (int i = 0; i < 4; ++i) {
        int n = bx * 32 + ty + i * 8;
        WT[(size_t)n * K + by * 32 + tx] = f2bf(tile[tx][ty + i * 8]);
    }
}

// ---------------- layernorm fp32 -> bf16 ----------------
__global__ __launch_bounds__(256) void layernorm_bf16(
    const float* __restrict__ X, const float* __restrict__ g,
    const float* __restrict__ b, unsigned short* __restrict__ Y)
{
    int row = blockIdx.x, t = threadIdx.x;
    const float4* xr = (const float4*)(X + (size_t)row * Dd);
    float4 v = xr[t];
    float s  = v.x + v.y + v.z + v.w;
    float s2 = v.x * v.x + v.y * v.y + v.z * v.z + v.w * v.w;
#pragma unroll
    for (int off = 32; off >= 1; off >>= 1) {
        s  += __shfl_down(s, off, 64);
        s2 += __shfl_down(s2, off, 64);
    }
    __shared__ float red[8];
    int wave = t >> 6, lane = t & 63;
    if (lane == 0) { red[wave] = s; red[4 + wave] = s2; }
    __syncthreads();
    float ts  = red[0] + red[1] + red[2] + red[3];
    float ts2 = red[4] + red[5] + red[6] + red[7];
    float mu  = ts * (1.0f / Dd);
    float var = ts2 * (1.0f / Dd) - mu * mu;
    float rstd = rsqrtf(var + 1e-5f);
    float4 gv = ((const float4*)g)[t];
    float4 bv = ((const float4*)b)[t];
    ushort4 o;
    o.x = f2bf((v.x - mu) * rstd * gv.x + bv.x);
    o.y = f2bf((v.y - mu) * rstd * gv.y + bv.y);
    o.z = f2bf((v.z - mu) * rstd * gv.z + bv.z);
    o.w = f2bf((v.w - mu) * rstd * gv.w + bv.w);
    ((ushort4*)(Y + (size_t)row * Dd))[t] = o;
}

// ---------------- GEMM: C = A[M,K] * BT[N,K]^T + bias ----------------
// BK=64, LDS chunk-XOR swizzle: LDS[row][cp] = G[row][cp ^ (row&7)] (16B chunks).
// MODE 0: out bf16 = A@B + bias
// MODE 1: out fp32 = A@B + bias + res
// MODE 2: out bf16 = gelu_new(A@B + bias)   (exp2-based, == tanh form)
template <int MODE>
__global__ __launch_bounds__(256, 2) void gemm_bt(
    const unsigned short* __restrict__ A,
    const unsigned short* __restrict__ BT,
    const float* __restrict__ bias,
    const float* __restrict__ res,
    void* __restrict__ out,
    int M, int N, int K)
{
    __shared__ short As[128 * 64];  // 16 KB
    __shared__ short Bs[128 * 64];  // 16 KB
    const int tid  = threadIdx.x;
    const int wave = tid >> 6, lane = tid & 63;
    const int quad = lane >> 4, l16 = lane & 15;
    const int wm = (wave >> 1) * 64, wn = (wave & 1) * 64;
    const int sw = l16 & 7;  // fragment-read swizzle selector
    const size_t rowA0 = (size_t)blockIdx.x * 128;
    const size_t rowB0 = (size_t)blockIdx.y * 128;

    floatx4 acc[4][4] = {};

    // staging decomposition: idx = tid + r*256, r=0..3
    int srow[4], scs[4];
#pragma unroll
    for (int r = 0; r < 4; ++r) {
        int idx = tid + r * 256;
        srow[r] = idx >> 3;
        scs[r]  = ((idx & 7) ^ (srow[r] & 7)) * 8;  // source k-offset (elements)
    }

    for (int k0 = 0; k0 < K; k0 += 64) {
#pragma unroll
        for (int r = 0; r < 4; ++r) {
            int idx = tid + r * 256;
            gl2lds16(A  + (rowA0 + srow[r]) * K + k0 + scs[r], As + idx * 8);
            gl2lds16(BT + (rowB0 + srow[r]) * K + k0 + scs[r], Bs + idx * 8);
        }
        __syncthreads();
#pragma unroll
        for (int ks = 0; ks < 2; ++ks) {
            short8 af[4], bfr[4];
#pragma unroll
            for (int mi = 0; mi < 4; ++mi)
                af[mi] = *(const short8*)(As + (wm + mi * 16 + l16) * 64
                                             + (((ks << 2) + quad) ^ sw) * 8);
#pragma unroll
            for (int ni = 0; ni < 4; ++ni)
                bfr[ni] = *(const short8*)(Bs + (wn + ni * 16 + l16) * 64
                                              + (((ks << 2) + quad) ^ sw) * 8);
#pragma unroll
            for (int mi = 0; mi < 4; ++mi)
#pragma unroll
                for (int ni = 0; ni < 4; ++ni)
                    acc[mi][ni] = __builtin_amdgcn_mfma_f32_16x16x32_bf16(
                        af[mi], bfr[ni], acc[mi][ni], 0, 0, 0);
        }
        __syncthreads();
    }

#pragma unroll
    for (int mi = 0; mi < 4; ++mi) {
#pragma unroll
        for (int ni = 0; ni < 4; ++ni) {
            size_t row = rowA0 + wm + mi * 16 + quad * 4;
            size_t col = rowB0 + wn + ni * 16 + l16;
            float bc = bias[col];
#pragma unroll
            for (int r = 0; r < 4; ++r) {
                float v = acc[mi][ni][r] + bc;
                if (MODE == 0) {
                    ((unsigned short*)out)[(row + r) * N + col] = f2bf(v);
                } else if (MODE == 1) {
                    ((float*)out)[(row + r) * N + col] = v + res[(row + r) * N + col];
                } else {
                    // gelu = v * rcp(1 + exp2(-2*log2e * c*(v+0.044715 v^3)))
                    float u = 0.7978845608028654f * (v + 0.044715f * v * v * v);
                    float e = __builtin_amdgcn_exp2f(-2.8853900817779268f * u);
                    float gl = v * __builtin_amdgcn_rcpf(1.0f + e);
                    ((unsigned short*)out)[(row + r) * N + col] = f2bf(gl);
                }
            }
        }
    }
}

// ---------------- MFMA flash attention (causal) ----------------
// Grid: B*H*4 = 512 blocks of 256 threads. Block (b,h,c4) processes query
// chunks {c4, 7-c4} of 128 rows -> uniform 18 K-tiles (64 keys) per block.
// S^T = K.Q^T (C-frag cols = queries -> per-lane softmax state), P^T via LDS,
// O^T = V^T.P^T. Q pre-scaled by 0.125*log2(e); softmax in exp2.
__global__ __launch_bounds__(256, 2) void attn_mfma(
    const unsigned short* __restrict__ qkv,  // [B*S][3072] bf16 q|k|v
    unsigned short* __restrict__ ctx)        // [B*S][1024] bf16
{
    __shared__ unsigned short Ks[64 * 72];
    __shared__ unsigned short VT[64 * 72];
    __shared__ unsigned short PT[128 * 72];

    const int tid  = threadIdx.x;
    const int wave = tid >> 6, lane = tid & 63;
    const int quad = lane >> 4, l16 = lane & 15;
    const int blk = blockIdx.x;
    const int c4 = blk & 3, h = (blk >> 2) & 15, b = blk >> 6;
    const size_t tokbase = (size_t)b * Ss;

    const int skey = tid & 63;
    const int sseg = tid >> 6;

    for (int ci = 0; ci < 2; ++ci) {
        const int chunk = ci ? (7 - c4) : c4;
        const int q0 = chunk * 128;

        short8 qf[2][2];
#pragma unroll
        for (int nb = 0; nb < 2; ++nb)
#pragma unroll
            for (int ks = 0; ks < 2; ++ks) {
                const short8* qp = (const short8*)(qkv
                    + (tokbase + q0 + wave * 32 + nb * 16 + l16) * 3072
                    + h * HD + ks * 32 + quad * 8);
                short8 v = *qp, o;
#pragma unroll
                for (int j = 0; j < 8; ++j)
                    o[j] = (short)f2bf(bf2f((unsigned short)v[j]) * 0.18033688011112042f);
                qf[nb][ks] = o;
            }

        floatx4 Oacc[4][2] = {};
        float mrow[2] = {-3.0e38f, -3.0e38f};
        float lrow[2] = {0.f, 0.f};

        const int nkt = 2 * (chunk + 1);
        for (int kt = 0; kt < nkt; ++kt) {
            __syncthreads();
            {
                const short8* kp = (const short8*)(qkv
                    + (tokbase + kt * 64 + skey) * 3072 + Dd + h * HD + sseg * 16);
                short8 k0 = kp[0], k1 = kp[1];
                *(short8*)(Ks + skey * 72 + sseg * 16)     = k0;
                *(short8*)(Ks + skey * 72 + sseg * 16 + 8) = k1;
                const short8* vp = (const short8*)(qkv
                    + (tokbase + kt * 64 + skey) * 3072 + 2 * Dd + h * HD + sseg * 16);
                short8 v0 = vp[0], v1 = vp[1];
#pragma unroll
                for (int j = 0; j < 8; ++j) {
                    VT[(sseg * 16 + j) * 72 + skey]     = (unsigned short)v0[j];
                    VT[(sseg * 16 + 8 + j) * 72 + skey] = (unsigned short)v1[j];
                }
            }
            __syncthreads();

            floatx4 sacc[4][2] = {};
#pragma unroll
            for (int ks = 0; ks < 2; ++ks) {
                short8 af[4];
#pragma unroll
                for (int mi = 0; mi < 4; ++mi)
                    af[mi] = *(const short8*)(Ks + (mi * 16 + l16) * 72 + ks * 32 + quad * 8);
#pragma unroll
                for (int mi = 0; mi < 4; ++mi)
#pragma unroll
                    for (int nb = 0; nb < 2; ++nb)
                        sacc[mi][nb] = __builtin_amdgcn_mfma_f32_16x16x32_bf16(
                            af[mi], qf[nb][ks], sacc[mi][nb], 0, 0, 0);
            }

            if (kt >= 2 * chunk) {
                const int dk = (kt - 2 * chunk) * 64;
#pragma unroll
                for (int nb = 0; nb < 2; ++nb) {
                    int qrow = wave * 32 + nb * 16 + l16;
#pragma unroll
                    for (int mi = 0; mi < 4; ++mi)
#pragma unroll
                        for (int r = 0; r < 4; ++r)
                            if (dk + mi * 16 + quad * 4 + r > qrow)
                                sacc[mi][nb][r] = -3.0e38f;
                }
            }

#pragma unroll
            for (int nb = 0; nb < 2; ++nb) {
                float mx = sacc[0][nb][0];
#pragma unroll
                for (int mi = 0; mi < 4; ++mi)
#pragma unroll
                    for (int r = 0; r < 4; ++r) mx = fmaxf(mx, sacc[mi][nb][r]);
                mx = fmaxf(mx, __shfl_xor(mx, 16, 64));
                mx = fmaxf(mx, __shfl_xor(mx, 32, 64));
                float mnew  = fmaxf(mrow[nb], mx);
                float alpha = __builtin_amdgcn_exp2f(mrow[nb] - mnew);
                float ls = 0.f;
#pragma unroll
                for (int mi = 0; mi < 4; ++mi) {
                    short4v pk;
#pragma unroll
                    for (int r = 0; r < 4; ++r) {
                        float p = __builtin_amdgcn_exp2f(sacc[mi][nb][r] - mnew);
                        ls += p;
                        pk[r] = (short)f2bf(p);
                    }
                    *(short4v*)(PT + (wave * 32 + nb * 16 + l16) * 72 + mi * 16 + quad * 4) = pk;
                }
                ls += __shfl_xor(ls, 16, 64);
                ls += __shfl_xor(ls, 32, 64);
                lrow[nb] = lrow[nb] * alpha + ls;
                mrow[nb] = mnew;
#pragma unroll
                for (int mi3 = 0; mi3 < 4; ++mi3) Oacc[mi3][nb] *= alpha;
            }
            asm volatile("s_waitcnt lgkmcnt(0)" ::: "memory");

#pragma unroll
            for (int ks2 = 0; ks2 < 2; ++ks2) {
                short8 av[4], bp[2];
#pragma unroll
                for (int mi3 = 0; mi3 < 4; ++mi3)
                    av[mi3] = *(const short8*)(VT + (mi3 * 16 + l16) * 72 + ks2 * 32 + quad * 8);
#pragma unroll
                for (int nb = 0; nb < 2; ++nb)
                    bp[nb] = *(const short8*)(PT + (wave * 32 + nb * 16 + l16) * 72 + ks2 * 32 + quad * 8);
#pragma unroll
                for (int mi3 = 0; mi3 < 4; ++mi3)
#pragma unroll
                    for (int nb = 0; nb < 2; ++nb)
                        Oacc[mi3][nb] = __builtin_amdgcn_mfma_f32_16x16x32_bf16(
                            av[mi3], bp[nb], Oacc[mi3][nb], 0, 0, 0);
            }
        }

#pragma unroll
        for (int nb = 0; nb < 2; ++nb) {
            float inv = 1.0f / lrow[nb];
#pragma unroll
            for (int mi3 = 0; mi3 < 4; ++mi3) {
                short4v ov;
#pragma unroll
                for (int r = 0; r < 4; ++r)
                    ov[r] = (short)f2bf(Oacc[mi3][nb][r] * inv);
                *(short4v*)(PT + (wave * 32 + nb * 16 + l16) * 72 + mi3 * 16 + quad * 4) = ov;
            }
        }
        asm volatile("s_waitcnt lgkmcnt(0)" ::: "memory");
        {
            int ql = lane >> 1, dbase = (lane & 1) * 32;
            unsigned short* op = ctx + (tokbase + q0 + wave * 32 + ql) * Dd + h * HD + dbase;
            const unsigned short* lp = PT + (wave * 32 + ql) * 72 + dbase;
#pragma unroll
            for (int i = 0; i < 4; ++i)
                ((short8*)op)[i] = *(const short8*)(lp + i * 8);
        }
    }
}

// ---------------- launch ----------------
extern "C" void kernel_launch(void* const* d_in, const int* in_sizes, int n_in,
                              void* d_out, int out_size, void* d_ws, size_t ws_size,
                              hipStream_t stream)
{
    const float* x        = (const float*)d_in[0];
    const float* ln1_g    = (const float*)d_in[1];
    const float* ln1_b    = (const float*)d_in[2];
    const float* c_attn_w = (const float*)d_in[3];
    const float* c_attn_b = (const float*)d_in[4];
    const float* c_proj_w = (const float*)d_in[5];
    const float* c_proj_b = (const float*)d_in[6];
    const float* ln2_g    = (const float*)d_in[7];
    const float* ln2_b    = (const float*)d_in[8];
    const float* fc_w     = (const float*)d_in[9];
    const float* fc_b     = (const float*)d_in[10];
    const float* proj_w   = (const float*)d_in[11];
    const float* proj_b   = (const float*)d_in[12];
    float* out = (float*)d_out;

    char* p = (char*)d_ws;
    auto alloc = [&](size_t bytes) {
        void* r = (void*)p;
        p += (bytes + 255) & ~(size_t)255;
        return r;
    };
    unsigned short* WaT  = (unsigned short*)alloc((size_t)3072 * 1024 * 2);
    unsigned short* WpT  = (unsigned short*)alloc((size_t)1024 * 1024 * 2);
    unsigned short* WfT  = (unsigned short*)alloc((size_t)4096 * 1024 * 2);
    unsigned short* Wp2T = (unsigned short*)alloc((size_t)1024 * 4096 * 2);
    unsigned short* h1   = (unsigned short*)alloc((size_t)MTOK * 1024 * 2);
    unsigned short* qkv  = (unsigned short*)alloc((size_t)MTOK * 3072 * 2);
    unsigned short* ctx  = (unsigned short*)alloc((size_t)MTOK * 1024 * 2);
    float*          hmid = (float*)alloc((size_t)MTOK * 1024 * 4);
    unsigned short* h2   = (unsigned short*)alloc((size_t)MTOK * 1024 * 2);
    unsigned short* ff1  = (unsigned short*)alloc((size_t)MTOK * 4096 * 2);

    transpose_w<<<dim3(3072 / 32, 1024 / 32), 256, 0, stream>>>(c_attn_w, WaT, 1024, 3072);
    transpose_w<<<dim3(1024 / 32, 1024 / 32), 256, 0, stream>>>(c_proj_w, WpT, 1024, 1024);
    transpose_w<<<dim3(4096 / 32, 1024 / 32), 256, 0, stream>>>(fc_w, WfT, 1024, 4096);
    transpose_w<<<dim3(1024 / 32, 4096 / 32), 256, 0, stream>>>(proj_w, Wp2T, 4096, 1024);

    layernorm_bf16<<<MTOK, 256, 0, stream>>>(x, ln1_g, ln1_b, h1);
    gemm_bt<0><<<dim3(64, 24), 256, 0, stream>>>(h1, WaT, c_attn_b, nullptr, qkv, MTOK, 3072, 1024);
    attn_mfma<<<Bb * Hh * 4, 256, 0, stream>>>(qkv, ctx);
    gemm_bt<1><<<dim3(64, 8), 256, 0, stream>>>(ctx, WpT, c_proj_b, x, hmid, MTOK, 1024, 1024);
    layernorm_bf16<<<MTOK, 256, 0, stream>>>(hmid, ln2_g, ln2_b, h2);
    gemm_bt<2><<<dim3(64, 32), 256, 0, stream>>>(h2, WfT, fc_b, nullptr, ff1, MTOK, 4096, 1024);
    gemm_bt<1><<<dim3(64, 8), 256, 0, stream>>>(ff1, Wp2T, proj_b, hmid, out, MTOK, 1024, 4096);
}

// Round 5
// 453.641 us; speedup vs baseline: 3.1616x; 1.0052x over previous
//
#include <hip/hip_runtime.h>
#include <cstdint>
#include <cmath>

// GPT-2 block: B=8, S=1024, D=1024, H=16, Hd=64.
// LN1 -> qkv GEMM -> MFMA flash attention -> proj GEMM(+res) -> LN2
//     -> fc GEMM(+fast GELU) -> proj2 GEMM(+res) -> out (fp32)
// GEMM: bf16 MFMA 16x16x32, 128x128 tile, BK=64.
//   A (activations): LDS-staged via global_load_lds, XOR-swizzled (0 conflicts).
//   B (weights): pre-packed fragment-major, loaded global->VGPR directly
//   (no LDS, no barrier dependency -> halved staging + LDS off critical path).

#define Bb 8
#define Ss 1024
#define Dd 1024
#define Hh 16
#define HD 64
#define MTOK 8192  // B*S

typedef __attribute__((ext_vector_type(4))) float  floatx4;
typedef __attribute__((ext_vector_type(8))) short  short8;
typedef __attribute__((ext_vector_type(4))) short  short4v;

__device__ __forceinline__ float bf2f(unsigned short u) {
    return __uint_as_float(((unsigned int)u) << 16);
}
__device__ __forceinline__ unsigned short f2bf(float f) {
    unsigned int u = __float_as_uint(f);
    u += 0x7FFFu + ((u >> 16) & 1u);   // RNE
    return (unsigned short)(u >> 16);
}

__device__ __forceinline__ void gl2lds16(const void* g, void* l) {
    __builtin_amdgcn_global_load_lds(
        (__attribute__((address_space(1))) void*)(g),
        (__attribute__((address_space(3))) void*)(l),
        16, 0, 0);
}

// ---------------- weight pack: fp32 [K][N] -> bf16 fragment-major ----------
// P[((nt*KC + kc)*64 + lane)*8 + j] = bf16(W[(kc*32 + (lane>>4)*8 + j)*N + nt*16 + (lane&15)])
// One wave per (nt, kc) tile.
__global__ __launch_bounds__(256) void pack_w(
    const float* __restrict__ W, unsigned short* __restrict__ P, int K, int N)
{
    const int KC = K >> 5;
    int tile = blockIdx.x * 4 + (threadIdx.x >> 6);
    int lane = threadIdx.x & 63;
    int nt = tile / KC, kc = tile - nt * KC;
    int l16 = lane & 15, quad = lane >> 4;
    const float* src = W + (size_t)(kc * 32 + quad * 8) * N + nt * 16 + l16;
    short8 o;
#pragma unroll
    for (int j = 0; j < 8; ++j) o[j] = (short)f2bf(src[(size_t)j * N]);
    *(short8*)(P + ((size_t)(nt * KC + kc) * 64 + lane) * 8) = o;
}

// ---------------- layernorm fp32 -> bf16 ----------------
__global__ __launch_bounds__(256) void layernorm_bf16(
    const float* __restrict__ X, const float* __restrict__ g,
    const float* __restrict__ b, unsigned short* __restrict__ Y)
{
    int row = blockIdx.x, t = threadIdx.x;
    const float4* xr = (const float4*)(X + (size_t)row * Dd);
    float4 v = xr[t];
    float s  = v.x + v.y + v.z + v.w;
    float s2 = v.x * v.x + v.y * v.y + v.z * v.z + v.w * v.w;
#pragma unroll
    for (int off = 32; off >= 1; off >>= 1) {
        s  += __shfl_down(s, off, 64);
        s2 += __shfl_down(s2, off, 64);
    }
    __shared__ float red[8];
    int wave = t >> 6, lane = t & 63;
    if (lane == 0) { red[wave] = s; red[4 + wave] = s2; }
    __syncthreads();
    float ts  = red[0] + red[1] + red[2] + red[3];
    float ts2 = red[4] + red[5] + red[6] + red[7];
    float mu  = ts * (1.0f / Dd);
    float var = ts2 * (1.0f / Dd) - mu * mu;
    float rstd = rsqrtf(var + 1e-5f);
    float4 gv = ((const float4*)g)[t];
    float4 bv = ((const float4*)b)[t];
    ushort4 o;
    o.x = f2bf((v.x - mu) * rstd * gv.x + bv.x);
    o.y = f2bf((v.y - mu) * rstd * gv.y + bv.y);
    o.z = f2bf((v.z - mu) * rstd * gv.z + bv.z);
    o.w = f2bf((v.w - mu) * rstd * gv.w + bv.w);
    ((ushort4*)(Y + (size_t)row * Dd))[t] = o;
}

// ---------------- GEMM: C = A[M,K] * W + bias (W packed frag-major) --------
// MODE 0: out bf16 = A@W + bias
// MODE 1: out fp32 = A@W + bias + res
// MODE 2: out bf16 = gelu_new(A@W + bias)   (exp2 form == tanh form)
template <int MODE>
__global__ __launch_bounds__(256, 2) void gemm_fw(
    const unsigned short* __restrict__ A,   // [M][K] bf16 row-major
    const unsigned short* __restrict__ BP,  // packed weight frags
    const float* __restrict__ bias,
    const float* __restrict__ res,
    void* __restrict__ out,
    int M, int N, int K)
{
    __shared__ short As[128 * 64];  // 16 KB (A only)
    const int tid  = threadIdx.x;
    const int wave = tid >> 6, lane = tid & 63;
    const int quad = lane >> 4, l16 = lane & 15;
    const int wm = (wave >> 1) * 64, wn = (wave & 1) * 64;
    const int sw = l16 & 7;
    const size_t rowA0 = (size_t)blockIdx.x * 128;
    const int KC = K >> 5;
    // this wave's 4 n-tiles start at tile nt0 = blockIdx.y*8 + (wave&1)*4;
    // tile nt is at element offset nt*KC*512 (layout: ((nt*KC+kc)*64+lane)*8)
    const unsigned short* bb = BP
        + ((size_t)(blockIdx.y * 8 + (wave & 1) * 4) * KC * 512 + (size_t)lane * 8);

    floatx4 acc[4][4] = {};

    int srow[4], scs[4];
#pragma unroll
    for (int r = 0; r < 4; ++r) {
        int idx = tid + r * 256;
        srow[r] = idx >> 3;
        scs[r]  = ((idx & 7) ^ (srow[r] & 7)) * 8;  // XOR chunk swizzle
    }

    for (int k0 = 0; k0 < K; k0 += 64) {
        // stage A tile (LDS), then issue B fragment loads (VGPR, overlap barrier)
#pragma unroll
        for (int r = 0; r < 4; ++r) {
            int idx = tid + r * 256;
            gl2lds16(A + (rowA0 + srow[r]) * K + k0 + scs[r], As + idx * 8);
        }
        const int kc0 = k0 >> 5;
        short8 bfr[2][4];
#pragma unroll
        for (int ks = 0; ks < 2; ++ks)
#pragma unroll
            for (int ni = 0; ni < 4; ++ni)
                bfr[ks][ni] = *(const short8*)(bb
                    + ((size_t)(ni * KC + kc0 + ks) * 512));
        __syncthreads();

#pragma unroll
        for (int ks = 0; ks < 2; ++ks) {
            short8 af[4];
#pragma unroll
            for (int mi = 0; mi < 4; ++mi)
                af[mi] = *(const short8*)(As + (wm + mi * 16 + l16) * 64
                                             + (((ks << 2) + quad) ^ sw) * 8);
#pragma unroll
            for (int mi = 0; mi < 4; ++mi)
#pragma unroll
                for (int ni = 0; ni < 4; ++ni)
                    acc[mi][ni] = __builtin_amdgcn_mfma_f32_16x16x32_bf16(
                        af[mi], bfr[ks][ni], acc[mi][ni], 0, 0, 0);
        }
        __syncthreads();
    }

#pragma unroll
    for (int mi = 0; mi < 4; ++mi) {
#pragma unroll
        for (int ni = 0; ni < 4; ++ni) {
            size_t row = rowA0 + wm + mi * 16 + quad * 4;
            size_t col = (size_t)blockIdx.y * 128 + wn + ni * 16 + l16;
            float bc = bias[col];
#pragma unroll
            for (int r = 0; r < 4; ++r) {
                float v = acc[mi][ni][r] + bc;
                if (MODE == 0) {
                    ((unsigned short*)out)[(row + r) * N + col] = f2bf(v);
                } else if (MODE == 1) {
                    ((float*)out)[(row + r) * N + col] = v + res[(row + r) * N + col];
                } else {
                    float u = 0.7978845608028654f * (v + 0.044715f * v * v * v);
                    float e = __builtin_amdgcn_exp2f(-2.8853900817779268f * u);
                    float gl = v * __builtin_amdgcn_rcpf(1.0f + e);
                    ((unsigned short*)out)[(row + r) * N + col] = f2bf(gl);
                }
            }
        }
    }
}

// ---------------- MFMA flash attention (causal) ----------------
// Grid: B*H*4 = 512 blocks of 256 threads. Block (b,h,c4) processes query
// chunks {c4, 7-c4} of 128 rows -> uniform 18 K-tiles (64 keys) per block.
// S^T = K.Q^T (C-frag cols = queries -> per-lane softmax state), P^T via LDS,
// O^T = V^T.P^T. Q pre-scaled by 0.125*log2(e); softmax in exp2.
__global__ __launch_bounds__(256, 2) void attn_mfma(
    const unsigned short* __restrict__ qkv,  // [B*S][3072] bf16 q|k|v
    unsigned short* __restrict__ ctx)        // [B*S][1024] bf16
{
    __shared__ unsigned short Ks[64 * 72];
    __shared__ unsigned short VT[64 * 72];
    __shared__ unsigned short PT[128 * 72];

    const int tid  = threadIdx.x;
    const int wave = tid >> 6, lane = tid & 63;
    const int quad = lane >> 4, l16 = lane & 15;
    const int blk = blockIdx.x;
    const int c4 = blk & 3, h = (blk >> 2) & 15, b = blk >> 6;
    const size_t tokbase = (size_t)b * Ss;

    const int skey = tid & 63;
    const int sseg = tid >> 6;

    for (int ci = 0; ci < 2; ++ci) {
        const int chunk = ci ? (7 - c4) : c4;
        const int q0 = chunk * 128;

        short8 qf[2][2];
#pragma unroll
        for (int nb = 0; nb < 2; ++nb)
#pragma unroll
            for (int ks = 0; ks < 2; ++ks) {
                const short8* qp = (const short8*)(qkv
                    + (tokbase + q0 + wave * 32 + nb * 16 + l16) * 3072
                    + h * HD + ks * 32 + quad * 8);
                short8 v = *qp, o;
#pragma unroll
                for (int j = 0; j < 8; ++j)
                    o[j] = (short)f2bf(bf2f((unsigned short)v[j]) * 0.18033688011112042f);
                qf[nb][ks] = o;
            }

        floatx4 Oacc[4][2] = {};
        float mrow[2] = {-3.0e38f, -3.0e38f};
        float lrow[2] = {0.f, 0.f};

        const int nkt = 2 * (chunk + 1);
        for (int kt = 0; kt < nkt; ++kt) {
            __syncthreads();
            {
                const short8* kp = (const short8*)(qkv
                    + (tokbase + kt * 64 + skey) * 3072 + Dd + h * HD + sseg * 16);
                short8 k0 = kp[0], k1 = kp[1];
                *(short8*)(Ks + skey * 72 + sseg * 16)     = k0;
                *(short8*)(Ks + skey * 72 + sseg * 16 + 8) = k1;
                const short8* vp = (const short8*)(qkv
                    + (tokbase + kt * 64 + skey) * 3072 + 2 * Dd + h * HD + sseg * 16);
                short8 v0 = vp[0], v1 = vp[1];
#pragma unroll
                for (int j = 0; j < 8; ++j) {
                    VT[(sseg * 16 + j) * 72 + skey]     = (unsigned short)v0[j];
                    VT[(sseg * 16 + 8 + j) * 72 + skey] = (unsigned short)v1[j];
                }
            }
            __syncthreads();

            floatx4 sacc[4][2] = {};
#pragma unroll
            for (int ks = 0; ks < 2; ++ks) {
                short8 af[4];
#pragma unroll
                for (int mi = 0; mi < 4; ++mi)
                    af[mi] = *(const short8*)(Ks + (mi * 16 + l16) * 72 + ks * 32 + quad * 8);
#pragma unroll
                for (int mi = 0; mi < 4; ++mi)
#pragma unroll
                    for (int nb = 0; nb < 2; ++nb)
                        sacc[mi][nb] = __builtin_amdgcn_mfma_f32_16x16x32_bf16(
                            af[mi], qf[nb][ks], sacc[mi][nb], 0, 0, 0);
            }

            if (kt >= 2 * chunk) {
                const int dk = (kt - 2 * chunk) * 64;
#pragma unroll
                for (int nb = 0; nb < 2; ++nb) {
                    int qrow = wave * 32 + nb * 16 + l16;
#pragma unroll
                    for (int mi = 0; mi < 4; ++mi)
#pragma unroll
                        for (int r = 0; r < 4; ++r)
                            if (dk + mi * 16 + quad * 4 + r > qrow)
                                sacc[mi][nb][r] = -3.0e38f;
                }
            }

#pragma unroll
            for (int nb = 0; nb < 2; ++nb) {
                float mx = sacc[0][nb][0];
#pragma unroll
                for (int mi = 0; mi < 4; ++mi)
#pragma unroll
                    for (int r = 0; r < 4; ++r) mx = fmaxf(mx, sacc[mi][nb][r]);
                mx = fmaxf(mx, __shfl_xor(mx, 16, 64));
                mx = fmaxf(mx, __shfl_xor(mx, 32, 64));
                float mnew  = fmaxf(mrow[nb], mx);
                float alpha = __builtin_amdgcn_exp2f(mrow[nb] - mnew);
                float ls = 0.f;
#pragma unroll
                for (int mi = 0; mi < 4; ++mi) {
                    short4v pk;
#pragma unroll
                    for (int r = 0; r < 4; ++r) {
                        float p = __builtin_amdgcn_exp2f(sacc[mi][nb][r] - mnew);
                        ls += p;
                        pk[r] = (short)f2bf(p);
                    }
                    *(short4v*)(PT + (wave * 32 + nb * 16 + l16) * 72 + mi * 16 + quad * 4) = pk;
                }
                ls += __shfl_xor(ls, 16, 64);
                ls += __shfl_xor(ls, 32, 64);
                lrow[nb] = lrow[nb] * alpha + ls;
                mrow[nb] = mnew;
#pragma unroll
                for (int mi3 = 0; mi3 < 4; ++mi3) Oacc[mi3][nb] *= alpha;
            }
            asm volatile("s_waitcnt lgkmcnt(0)" ::: "memory");

#pragma unroll
            for (int ks2 = 0; ks2 < 2; ++ks2) {
                short8 av[4], bp[2];
#pragma unroll
                for (int mi3 = 0; mi3 < 4; ++mi3)
                    av[mi3] = *(const short8*)(VT + (mi3 * 16 + l16) * 72 + ks2 * 32 + quad * 8);
#pragma unroll
                for (int nb = 0; nb < 2; ++nb)
                    bp[nb] = *(const short8*)(PT + (wave * 32 + nb * 16 + l16) * 72 + ks2 * 32 + quad * 8);
#pragma unroll
                for (int mi3 = 0; mi3 < 4; ++mi3)
#pragma unroll
                    for (int nb = 0; nb < 2; ++nb)
                        Oacc[mi3][nb] = __builtin_amdgcn_mfma_f32_16x16x32_bf16(
                            av[mi3], bp[nb], Oacc[mi3][nb], 0, 0, 0);
            }
        }

#pragma unroll
        for (int nb = 0; nb < 2; ++nb) {
            float inv = 1.0f / lrow[nb];
#pragma unroll
            for (int mi3 = 0; mi3 < 4; ++mi3) {
                short4v ov;
#pragma unroll
                for (int r = 0; r < 4; ++r)
                    ov[r] = (short)f2bf(Oacc[mi3][nb][r] * inv);
                *(short4v*)(PT + (wave * 32 + nb * 16 + l16) * 72 + mi3 * 16 + quad * 4) = ov;
            }
        }
        asm volatile("s_waitcnt lgkmcnt(0)" ::: "memory");
        {
            int ql = lane >> 1, dbase = (lane & 1) * 32;
            unsigned short* op = ctx + (tokbase + q0 + wave * 32 + ql) * Dd + h * HD + dbase;
            const unsigned short* lp = PT + (wave * 32 + ql) * 72 + dbase;
#pragma unroll
            for (int i = 0; i < 4; ++i)
                ((short8*)op)[i] = *(const short8*)(lp + i * 8);
        }
    }
}

// ---------------- launch ----------------
extern "C" void kernel_launch(void* const* d_in, const int* in_sizes, int n_in,
                              void* d_out, int out_size, void* d_ws, size_t ws_size,
                              hipStream_t stream)
{
    const float* x        = (const float*)d_in[0];
    const float* ln1_g    = (const float*)d_in[1];
    const float* ln1_b    = (const float*)d_in[2];
    const float* c_attn_w = (const float*)d_in[3];
    const float* c_attn_b = (const float*)d_in[4];
    const float* c_proj_w = (const float*)d_in[5];
    const float* c_proj_b = (const float*)d_in[6];
    const float* ln2_g    = (const float*)d_in[7];
    const float* ln2_b    = (const float*)d_in[8];
    const float* fc_w     = (const float*)d_in[9];
    const float* fc_b     = (const float*)d_in[10];
    const float* proj_w   = (const float*)d_in[11];
    const float* proj_b   = (const float*)d_in[12];
    float* out = (float*)d_out;

    char* p = (char*)d_ws;
    auto alloc = [&](size_t bytes) {
        void* r = (void*)p;
        p += (bytes + 255) & ~(size_t)255;
        return r;
    };
    unsigned short* WaP  = (unsigned short*)alloc((size_t)3072 * 1024 * 2);
    unsigned short* WpP  = (unsigned short*)alloc((size_t)1024 * 1024 * 2);
    unsigned short* WfP  = (unsigned short*)alloc((size_t)4096 * 1024 * 2);
    unsigned short* Wp2P = (unsigned short*)alloc((size_t)1024 * 4096 * 2);
    unsigned short* h1   = (unsigned short*)alloc((size_t)MTOK * 1024 * 2);
    unsigned short* qkv  = (unsigned short*)alloc((size_t)MTOK * 3072 * 2);
    unsigned short* ctx  = (unsigned short*)alloc((size_t)MTOK * 1024 * 2);
    float*          hmid = (float*)alloc((size_t)MTOK * 1024 * 4);
    unsigned short* h2   = (unsigned short*)alloc((size_t)MTOK * 1024 * 2);
    unsigned short* ff1  = (unsigned short*)alloc((size_t)MTOK * 4096 * 2);

    pack_w<<<(3072 / 16) * (1024 / 32) / 4, 256, 0, stream>>>(c_attn_w, WaP, 1024, 3072);
    pack_w<<<(1024 / 16) * (1024 / 32) / 4, 256, 0, stream>>>(c_proj_w, WpP, 1024, 1024);
    pack_w<<<(4096 / 16) * (1024 / 32) / 4, 256, 0, stream>>>(fc_w, WfP, 1024, 4096);
    pack_w<<<(1024 / 16) * (4096 / 32) / 4, 256, 0, stream>>>(proj_w, Wp2P, 4096, 1024);

    layernorm_bf16<<<MTOK, 256, 0, stream>>>(x, ln1_g, ln1_b, h1);
    gemm_fw<0><<<dim3(64, 24), 256, 0, stream>>>(h1, WaP, c_attn_b, nullptr, qkv, MTOK, 3072, 1024);
    attn_mfma<<<Bb * Hh * 4, 256, 0, stream>>>(qkv, ctx);
    gemm_fw<1><<<dim3(64, 8), 256, 0, stream>>>(ctx, WpP, c_proj_b, x, hmid, MTOK, 1024, 1024);
    layernorm_bf16<<<MTOK, 256, 0, stream>>>(hmid, ln2_g, ln2_b, h2);
    gemm_fw<2><<<dim3(64, 32), 256, 0, stream>>>(h2, WfP, fc_b, nullptr, ff1, MTOK, 4096, 1024);
    gemm_fw<1><<<dim3(64, 8), 256, 0, stream>>>(ff1, Wp2P, proj_b, hmid, out, MTOK, 1024, 4096);
}